// Round 6
// baseline (100.648 us; speedup 1.0000x reference)
//
#include <hip/hip_runtime.h>
#include <math.h>

#define NSP 4096   // H*W
#define CC  128    // channels
#define CIC 64     // inter channels
#define NB  4      // batch
#define LOG2E 1.4426950408889634f

typedef unsigned short u16;
typedef short s8bf __attribute__((ext_vector_type(8)));
typedef float f32x4 __attribute__((ext_vector_type(4)));

#define MFMA(a, b, c) __builtin_amdgcn_mfma_f32_16x16x32_bf16(a, b, c, 0, 0, 0)

// workspace byte offsets
#define WSB_PB    0                         // bf16 [B][128][NSP] (g:0-63, theta*log2e:64-127)
#define WSB_PH    (NB * CC * NSP * 2)       // bf16 [B][NSP][64] phi token-major
#define WSB_Y     (WSB_PH + NB * NSP * CIC * 2)    // f32 [B][64][NSP]
#define WSB_WT    (WSB_Y + NB * CIC * NSP * 4)     // f32 [128][192] proj weights transposed
#define WSB_WT2   (WSB_WT + CC * 192 * 4)          // f32 [64][128] wconv weights transposed
#define WSB_PARTS (WSB_WT2 + CIC * CC * 4)         // f32 [128][4][2] stats partials

__device__ __forceinline__ u16 f2bf(float f) {
    union { float f; unsigned u; } v; v.f = f;
    unsigned r = v.u + 0x7fffu + ((v.u >> 16) & 1u);
    return (u16)(r >> 16);
}

// -------------------- Kernel 0: weight transpose prep ---------------------------
// grid (CC), block 256. wT[c][o] (o: g 0-63, theta*log2e 64-127, phi 128-191);
// wT2[ci][c] = w_w[c][ci].
__global__ __launch_bounds__(256) void prep_kernel(
    const float* __restrict__ g_w, const float* __restrict__ t_w,
    const float* __restrict__ p_w, const float* __restrict__ w_w,
    float* __restrict__ wT, float* __restrict__ wT2)
{
    const int c = blockIdx.x;
    const int o = threadIdx.x;
    if (o < 192) {
        float v;
        if (o < 64)       v = g_w[o * CC + c];
        else if (o < 128) v = t_w[(o - 64) * CC + c] * LOG2E;
        else              v = p_w[(o - 128) * CC + c];
        wT[c * 192 + o] = v;
    }
    if (o < CIC)
        wT2[o * CC + c] = w_w[c * CIC + o];
}

// -------------------- Kernel 1: fused 1x1 projections ---------------------------
// grid (NSP/32, NB), block 256 = 4 waves. Wave -> 8 tokens; lane -> 3 out-channels.
// Weights coalesced from L2 (wT), x via wave-broadcast loads. LDS only for
// coalesced bf16 output + phi transpose.
__global__ __launch_bounds__(256) void proj_kernel(
    const float* __restrict__ x, const float* __restrict__ wT,
    const float* __restrict__ g_b, const float* __restrict__ t_b,
    const float* __restrict__ p_b,
    u16* __restrict__ PB, u16* __restrict__ ph_tm)
{
    __shared__ u16 Ot[192][40];   // [o][token] bf16, 80B rows (16B aligned)

    const int b    = blockIdx.y;
    const int n0   = blockIdx.x * 32;
    const int tid  = threadIdx.x;
    const int lane = tid & 63;
    const int wv   = tid >> 6;
    const int t0   = wv * 8;

    float acc[3][8];
    {
        float b0 = g_b[lane], b1 = t_b[lane] * LOG2E, b2 = p_b[lane];
        #pragma unroll
        for (int t = 0; t < 8; ++t) { acc[0][t] = b0; acc[1][t] = b1; acc[2][t] = b2; }
    }

    const float* xb = x + (size_t)b * CC * NSP + n0 + t0;
    #pragma unroll 4
    for (int c = 0; c < CC; ++c) {
        f32x4 xv0 = *(const f32x4*)(xb + (size_t)c * NSP);
        f32x4 xv1 = *(const f32x4*)(xb + (size_t)c * NSP + 4);
        float w0 = wT[c * 192 + lane];
        float w1 = wT[c * 192 + 64 + lane];
        float w2 = wT[c * 192 + 128 + lane];
        #pragma unroll
        for (int t = 0; t < 4; ++t) {
            acc[0][t]     += w0 * xv0[t];
            acc[0][4 + t] += w0 * xv1[t];
            acc[1][t]     += w1 * xv0[t];
            acc[1][4 + t] += w1 * xv1[t];
            acc[2][t]     += w2 * xv0[t];
            acc[2][4 + t] += w2 * xv1[t];
        }
    }

    #pragma unroll
    for (int p = 0; p < 3; ++p)
        #pragma unroll
        for (int t = 0; t < 8; ++t)
            Ot[lane + 64 * p][t0 + t] = f2bf(acc[p][t]);
    __syncthreads();

    // g + theta (rows 0..127) -> PB channel-major, 16B coalesced chunks
    u16* Pb = PB + (size_t)b * CC * NSP + n0;
    #pragma unroll
    for (int k = 0; k < 2; ++k) {
        int idx = tid + (k << 8);          // 0..511
        int row = idx >> 2, ch = idx & 3;
        ushort4 v0 = *(const ushort4*)&Ot[row][ch * 8];
        ushort4 v1 = *(const ushort4*)&Ot[row][ch * 8 + 4];
        *(ushort4*)(Pb + (size_t)row * NSP + ch * 8)     = v0;
        *(ushort4*)(Pb + (size_t)row * NSP + ch * 8 + 4) = v1;
    }
    // phi (rows 128..191) -> token-major
    u16* dst = ph_tm + ((size_t)b * NSP + n0) * 64;
    #pragma unroll
    for (int k = 0; k < 2; ++k) {
        int fi = tid + (k << 8);           // 0..511
        int t = fi >> 4, c4 = (fi & 15) << 2;
        ushort4 v;
        v.x = Ot[128 + c4][t]; v.y = Ot[128 + c4 + 1][t];
        v.z = Ot[128 + c4 + 2][t]; v.w = Ot[128 + c4 + 3][t];
        *(ushort4*)(dst + (size_t)t * 64 + c4) = v;
    }
}

// -------------------- Kernel 2: MFMA attention, LDS-staged K/V ------------------
// grid (NSP/64, NB), block 512 = 8 waves: q-strip s=w&3 (16 rows), KV-half h=w>>2.
// Double-buffered K/V staging; shift-softmax p = exp2(QK - 32) via MFMA C-init.
// P strip: 160B rows + XOR chunk swizzle (chunk ^= (row>>1)&7) -> conflict-free.
__global__ __launch_bounds__(512, 2) void attn_kernel(
    const u16* __restrict__ PB, const u16* __restrict__ ph_tm,
    float* __restrict__ y)
{
    const int b    = blockIdx.y;
    const int q0   = blockIdx.x << 6;
    const int tid  = threadIdx.x;
    const int lane = tid & 63;
    const int w    = tid >> 6;       // 0..7
    const int s    = w & 3;          // q strip
    const int h    = w >> 2;         // kv half
    const int l15  = lane & 15;
    const int g16  = lane >> 4;

    __shared__ __align__(16) char KV[2][2][2][8192];
    __shared__ __align__(16) u16 Plds[8][16][80];
    __shared__ float Om[4][16][68];
    __shared__ float Lm[4][16];

    const u16* gp  = PB + (size_t)b * CC * NSP;           // g  cm [64][NSP]
    const u16* thc = gp + (size_t)CIC * NSP;              // theta cm (log2e-scaled)
    const u16* php = ph_tm + (size_t)b * NSP * 64;        // phi tm [NSP][64]

    const int srow = tid >> 3;
    const int scol = tid & 7;
    const int ldst = srow * 128 + (((scol ^ (srow & 7)) & 7) << 4);

    float4 rK0, rK1, rV0, rV1;
    auto load_t = [&](int t) {
        const int m0 = t << 6;
        rK0 = *(const float4*)(php + ((size_t)(       m0 + srow) << 6) + (scol << 3));
        rK1 = *(const float4*)(php + ((size_t)(2048 + m0 + srow) << 6) + (scol << 3));
        rV0 = *(const float4*)(gp + (size_t)srow * NSP +        m0 + (scol << 3));
        rV1 = *(const float4*)(gp + (size_t)srow * NSP + 2048 + m0 + (scol << 3));
    };
    auto write_t = [&](int buf) {
        *(float4*)(&KV[buf][0][0][0] + ldst) = rK0;
        *(float4*)(&KV[buf][0][1][0] + ldst) = rK1;
        *(float4*)(&KV[buf][1][0][0] + ldst) = rV0;
        *(float4*)(&KV[buf][1][1][0] + ldst) = rV1;
    };

    // Q fragments (once)
    s8bf qa0, qa1;
    const int qtok = q0 + s * 16 + l15;
    #pragma unroll
    for (int j = 0; j < 8; ++j) {
        qa0[j] = (short)thc[(size_t)(g16 * 8 + j) * NSP + qtok];
        qa1[j] = (short)thc[(size_t)(32 + g16 * 8 + j) * NSP + qtok];
    }

    const s8bf ones = {0x3F80, 0x3F80, 0x3F80, 0x3F80, 0x3F80, 0x3F80, 0x3F80, 0x3F80};
    const f32x4 cinit = {-32.f, -32.f, -32.f, -32.f};

    f32x4 Ov[4];
    f32x4 lr = (f32x4){0.f, 0.f, 0.f, 0.f};
    #pragma unroll
    for (int c = 0; c < 4; ++c) Ov[c] = (f32x4){0.f, 0.f, 0.f, 0.f};

    load_t(0); write_t(0); load_t(1);
    __syncthreads();

    // P swizzle constants for this lane
    const int pin   = l15 & 7;                 // within-chunk element
    const int pchb  = l15 >> 3;                // chunk base bit
    const int rmask = (g16 ^ ((l15 >> 1) & 7)) << 3;        // pa0 read offset
    const int rmask1 = ((4 + g16) ^ ((l15 >> 1) & 7)) << 3; // pa1 read offset

    for (int t = 0; t < 32; ++t) {
        const int buf = t & 1;
        const char* Kb = &KV[buf][0][h][0];
        const char* Vb = &KV[buf][1][h][0];

        // ---- QK^T from swizzled LDS K tile ----
        f32x4 sv[4];
        __builtin_amdgcn_s_setprio(1);
        #pragma unroll
        for (int c = 0; c < 4; ++c) {
            const int tok = c * 16 + l15;
            const int sx  = (tok & 7) << 4;
            s8bf k0 = *(const s8bf*)(Kb + tok * 128 + ((g16 * 16)      ^ sx));
            s8bf k1 = *(const s8bf*)(Kb + tok * 128 + ((g16 * 16 + 64) ^ sx));
            sv[c] = MFMA(qa0, k0, cinit);
            sv[c] = MFMA(qa1, k1, sv[c]);
        }
        __builtin_amdgcn_s_setprio(0);

        // ---- p = exp2(s) -> swizzled bf16 P strip ----
        u16 (&Pl)[16][80] = Plds[w];
        #pragma unroll
        for (int c = 0; c < 4; ++c) {
            #pragma unroll
            for (int r = 0; r < 4; ++r) {
                const int row = g16 * 4 + r;
                const int swc = ((c * 2 + pchb) ^ ((row >> 1) & 7)) << 3;
                Pl[row][swc | pin] = f2bf(__builtin_amdgcn_exp2f(sv[c][r]));
            }
        }

        // ---- P fragments; l via ones-MFMA; PV from swizzled LDS V tile ----
        s8bf pa0 = *(const s8bf*)&Pl[l15][rmask];
        s8bf pa1 = *(const s8bf*)&Pl[l15][rmask1];
        __builtin_amdgcn_s_setprio(1);
        lr = MFMA(pa0, ones, lr);
        lr = MFMA(pa1, ones, lr);
        #pragma unroll
        for (int c = 0; c < 4; ++c) {
            const int ci = c * 16 + l15;
            const int sx = (ci & 7) << 4;
            s8bf v0 = *(const s8bf*)(Vb + ci * 128 + ((g16 * 16)      ^ sx));
            s8bf v1 = *(const s8bf*)(Vb + ci * 128 + ((g16 * 16 + 64) ^ sx));
            Ov[c] = MFMA(pa0, v0, Ov[c]);
            Ov[c] = MFMA(pa1, v1, Ov[c]);
        }
        __builtin_amdgcn_s_setprio(0);

        if (t < 31) {
            write_t(buf ^ 1);
            if (t < 30) load_t(t + 2);
        }
        __syncthreads();
    }

    // ---- merge the 2 KV halves (plain adds; no max state) ----
    if (h == 1) {
        #pragma unroll
        for (int c = 0; c < 4; ++c) {
            #pragma unroll
            for (int r = 0; r < 4; ++r)
                Om[s][g16 * 4 + r][c * 16 + l15] = Ov[c][r];
        }
        if (l15 == 0) {
            #pragma unroll
            for (int r = 0; r < 4; ++r) Lm[s][g16 * 4 + r] = lr[r];
        }
    }
    __syncthreads();
    if (h == 0) {
        float inv[4];
        #pragma unroll
        for (int r = 0; r < 4; ++r) inv[r] = 1.0f / (lr[r] + Lm[s][g16 * 4 + r]);
        #pragma unroll
        for (int c = 0; c < 4; ++c) {
            #pragma unroll
            for (int r = 0; r < 4; ++r) {
                int row = g16 * 4 + r, col = c * 16 + l15;
                Om[s][row][col] = (Ov[c][r] + Om[s][row][col]) * inv[r];
            }
        }
    }
    __syncthreads();

    // ---- coalesced y write: 64 ci x 64 q ----
    #pragma unroll
    for (int k = 0; k < 2; ++k) {
        int idx = tid + (k << 9);        // 0..1023
        int ci = idx >> 4, q4 = (idx & 15) << 2;
        int ss = q4 >> 4, r0 = q4 & 15;
        float4 v;
        v.x = Om[ss][r0][ci]; v.y = Om[ss][r0 + 1][ci];
        v.z = Om[ss][r0 + 2][ci]; v.w = Om[ss][r0 + 3][ci];
        *(float4*)&y[((size_t)b * CIC + ci) * NSP + q0 + q4] = v;
    }
}

// -------------------- Kernel 3: W 1x1 conv -> w_y into d_out --------------------
// grid (NSP/32, NB), block 256 = 4 waves. Wave -> 8 tokens; lane -> 2 out-channels.
__global__ __launch_bounds__(256) void wconv_kernel(
    const float* __restrict__ y, const float* __restrict__ wT2,
    const float* __restrict__ w_b, float* __restrict__ out)
{
    __shared__ float Ot[CC][36];   // [c][token] f32, 144B rows

    const int b    = blockIdx.y;
    const int n0   = blockIdx.x * 32;
    const int tid  = threadIdx.x;
    const int lane = tid & 63;
    const int wv   = tid >> 6;
    const int t0   = wv * 8;

    float acc[2][8];
    #pragma unroll
    for (int t = 0; t < 8; ++t) { acc[0][t] = 0.f; acc[1][t] = 0.f; }

    const float* yb = y + (size_t)b * CIC * NSP + n0 + t0;
    #pragma unroll 4
    for (int ci = 0; ci < CIC; ++ci) {
        f32x4 y0 = *(const f32x4*)(yb + (size_t)ci * NSP);
        f32x4 y1 = *(const f32x4*)(yb + (size_t)ci * NSP + 4);
        float w0 = wT2[ci * CC + lane];
        float w1 = wT2[ci * CC + 64 + lane];
        #pragma unroll
        for (int t = 0; t < 4; ++t) {
            acc[0][t]     += w0 * y0[t];
            acc[0][4 + t] += w0 * y1[t];
            acc[1][t]     += w1 * y0[t];
            acc[1][4 + t] += w1 * y1[t];
        }
    }

    float b0 = w_b[lane], b1 = w_b[64 + lane];
    #pragma unroll
    for (int t = 0; t < 8; ++t) {
        Ot[lane][t0 + t]      = acc[0][t] + b0;
        Ot[64 + lane][t0 + t] = acc[1][t] + b1;
    }
    __syncthreads();

    float* ob = out + (size_t)b * CC * NSP + n0;
    #pragma unroll
    for (int k = 0; k < 4; ++k) {
        int idx = tid + (k << 8);        // 0..1023
        int row = idx >> 3, ch = idx & 7;
        float4 v = *(const float4*)&Ot[row][ch * 4];
        *(float4*)(ob + (size_t)row * NSP + ch * 4) = v;
    }
}

// -------------------- Kernel 4: per-channel partial stats -----------------------
// grid (CC*4), block 256. Block -> (c, quarter of B*N). Writes [c][qd][2] partials.
__global__ __launch_bounds__(256) void stats_kernel(
    const float* __restrict__ wy, float* __restrict__ parts)
{
    const int c   = blockIdx.x >> 2;
    const int qd  = blockIdx.x & 3;
    const int tid = threadIdx.x;
    float s = 0.f, ss = 0.f;
    #pragma unroll 4
    for (int k = 0; k < 16; ++k) {
        int i = qd * 4096 + k * 256 + tid;   // 0..16383
        int b = i >> 12, n = i & (NSP - 1);
        float v = wy[((size_t)b * CC + c) * NSP + n];
        s += v; ss += v * v;
    }
    #pragma unroll
    for (int off = 32; off > 0; off >>= 1) {
        s  += __shfl_down(s, off, 64);
        ss += __shfl_down(ss, off, 64);
    }
    __shared__ float sred[4], ssred[4];
    const int wid = tid >> 6, lane = tid & 63;
    if (lane == 0) { sred[wid] = s; ssred[wid] = ss; }
    __syncthreads();
    if (tid == 0) {
        parts[(c * 4 + qd) * 2]     = sred[0] + sred[1] + sred[2] + sred[3];
        parts[(c * 4 + qd) * 2 + 1] = ssred[0] + ssred[1] + ssred[2] + ssred[3];
    }
}

// -------------------- Kernel 5: BN finalize + residual (in-place) ---------------
__global__ __launch_bounds__(256) void bn_kernel(
    const float* __restrict__ x, const float* __restrict__ parts,
    const float* __restrict__ gamma, const float* __restrict__ beta,
    float* __restrict__ out)
{
    const int i = blockIdx.x * 256 + threadIdx.x;
    const int c = (i >> 10) & (CC - 1);
    float s  = parts[c * 8]     + parts[c * 8 + 2] + parts[c * 8 + 4] + parts[c * 8 + 6];
    float ss = parts[c * 8 + 1] + parts[c * 8 + 3] + parts[c * 8 + 5] + parts[c * 8 + 7];
    float mean = s * (1.0f / 16384.0f);
    float var  = ss * (1.0f / 16384.0f) - mean * mean;
    float istd = rsqrtf(var + 1e-5f);
    float ga = gamma[c] * istd;
    float be = beta[c] - mean * ga;
    float4 wy = ((const float4*)out)[i];
    float4 xv = ((const float4*)x)[i];
    float4 o;
    o.x = wy.x * ga + be + xv.x;
    o.y = wy.y * ga + be + xv.y;
    o.z = wy.z * ga + be + xv.z;
    o.w = wy.w * ga + be + xv.w;
    ((float4*)out)[i] = o;
}

extern "C" void kernel_launch(void* const* d_in, const int* in_sizes, int n_in,
                              void* d_out, int out_size, void* d_ws, size_t ws_size,
                              hipStream_t stream)
{
    const float* x    = (const float*)d_in[0];
    const float* g_w  = (const float*)d_in[1];
    const float* g_b  = (const float*)d_in[2];
    const float* t_w  = (const float*)d_in[3];
    const float* t_b  = (const float*)d_in[4];
    const float* p_w  = (const float*)d_in[5];
    const float* p_b  = (const float*)d_in[6];
    const float* w_w  = (const float*)d_in[7];
    const float* w_b  = (const float*)d_in[8];
    const float* bn_g = (const float*)d_in[9];
    const float* bn_b = (const float*)d_in[10];
    float* out = (float*)d_out;
    char* ws8  = (char*)d_ws;

    u16*   PB    = (u16*)(ws8 + WSB_PB);
    u16*   PH    = (u16*)(ws8 + WSB_PH);
    float* y     = (float*)(ws8 + WSB_Y);
    float* wT    = (float*)(ws8 + WSB_WT);
    float* wT2   = (float*)(ws8 + WSB_WT2);
    float* parts = (float*)(ws8 + WSB_PARTS);

    prep_kernel <<<dim3(CC), 256, 0, stream>>>(g_w, t_w, p_w, w_w, wT, wT2);
    proj_kernel <<<dim3(NSP / 32, NB), 256, 0, stream>>>(x, wT, g_b, t_b, p_b, PB, PH);
    attn_kernel <<<dim3(NSP / 64, NB), 512, 0, stream>>>(PB, PH, y);
    wconv_kernel<<<dim3(NSP / 32, NB), 256, 0, stream>>>(y, wT2, w_b, out);
    stats_kernel<<<dim3(CC * 4), 256, 0, stream>>>(out, parts);
    bn_kernel   <<<dim3(2048), 256, 0, stream>>>(x, parts, bn_g, bn_b, out);
}

// Round 8
// 78.805 us; speedup vs baseline: 1.2772x; 1.2772x over previous
//
#include <hip/hip_runtime.h>
#include <math.h>

#define NSP 4096   // H*W
#define CC  128    // channels
#define CIC 64     // inter channels
#define NB  4      // batch
#define LOG2E 1.4426950408889634f

typedef unsigned short u16;
typedef short s8bf __attribute__((ext_vector_type(8)));
typedef float f32x4 __attribute__((ext_vector_type(4)));
typedef float f32x2 __attribute__((ext_vector_type(2)));

#define MFMA(a, b, c) __builtin_amdgcn_mfma_f32_16x16x32_bf16(a, b, c, 0, 0, 0)

// workspace byte offsets
#define WSB_PB    0                         // bf16 [B][128][NSP] (g:0-63, theta*log2e:64-127)
#define WSB_PH    (NB * CC * NSP * 2)       // bf16 [B][NSP][64] phi token-major
#define WSB_Y     (WSB_PH + NB * NSP * CIC * 2)    // f32 [B][64][NSP]
#define WSB_WT4   (WSB_Y + NB * CIC * NSP * 4)     // f32 [128][64][4] proj weights {g,th,ph,0}
#define WSB_WT2P  (WSB_WT4 + CC * 256 * 4)         // f32 [64][64][2] wconv weight pairs
#define WSB_PARTS (WSB_WT2P + CIC * CC * 4)        // f32 [128][4][2] stats partials

__device__ __forceinline__ u16 f2bf(float f) {
    union { float f; unsigned u; } v; v.f = f;
    unsigned r = v.u + 0x7fffu + ((v.u >> 16) & 1u);
    return (u16)(r >> 16);
}

// -------------------- Kernel 0: weight repack prep ------------------------------
// grid (CC), block 256.
__global__ __launch_bounds__(256) void prep_kernel(
    const float* __restrict__ g_w, const float* __restrict__ t_w,
    const float* __restrict__ p_w, const float* __restrict__ w_w,
    float* __restrict__ wT4, float* __restrict__ wT2p)
{
    const int c = blockIdx.x;
    const int o = threadIdx.x;
    if (o < 192) {
        float v;
        if (o < 64)       v = g_w[o * CC + c];
        else if (o < 128) v = t_w[(o - 64) * CC + c] * LOG2E;
        else              v = p_w[(o - 128) * CC + c];
        wT4[(c << 8) + ((o & 63) << 2) + (o >> 6)] = v;
    } else {
        wT4[(c << 8) + ((o - 192) << 2) + 3] = 0.f;
    }
    if (o < CIC)
        wT2p[(o << 7) + ((c & 63) << 1) + (c >> 6)] = w_w[c * CIC + o];
}

// -------------------- Kernel 1: fused 1x1 projections ---------------------------
// grid (NSP/32, NB), block 512 = 8 waves; wave -> 4 tokens, lane -> 3 out-chans.
// x tile staged in LDS (broadcast reads); weights = 1 coalesced dwordx4/iter.
__global__ __launch_bounds__(512) void proj_kernel(
    const float* __restrict__ x, const float* __restrict__ wT4,
    const float* __restrict__ g_b, const float* __restrict__ t_b,
    const float* __restrict__ p_b,
    u16* __restrict__ PB, u16* __restrict__ ph_tm)
{
    __shared__ float Xs[CC][36];   // 18.4 KB, rows 144B (16B-mult)
    __shared__ u16 Ot[192][40];    // 15.4 KB, rows 80B (16B-mult)

    const int b    = blockIdx.y;
    const int n0   = blockIdx.x * 32;
    const int tid  = threadIdx.x;
    const int lane = tid & 63;
    const int wv   = tid >> 6;     // 0..7
    const int t0   = wv * 4;

    // stage x tile [128 ch][32 tok]
    const float* xb = x + (size_t)b * CC * NSP + n0;
    #pragma unroll
    for (int k = 0; k < 2; ++k) {
        int idx = tid + (k << 9);          // 0..1023
        int c = idx >> 3, t4 = (idx & 7) << 2;
        *(f32x4*)&Xs[c][t4] = *(const f32x4*)(xb + (size_t)c * NSP + t4);
    }
    __syncthreads();

    float acc[3][4];
    {
        float b0 = g_b[lane], b1 = t_b[lane] * LOG2E, b2 = p_b[lane];
        #pragma unroll
        for (int t = 0; t < 4; ++t) { acc[0][t] = b0; acc[1][t] = b1; acc[2][t] = b2; }
    }

    const float* wp = wT4 + (lane << 2);
    #pragma unroll 8
    for (int c = 0; c < CC; ++c) {
        f32x4 wv4 = *(const f32x4*)(wp + (c << 8));
        f32x4 xv  = *(const f32x4*)&Xs[c][t0];
        #pragma unroll
        for (int t = 0; t < 4; ++t) {
            acc[0][t] += wv4[0] * xv[t];
            acc[1][t] += wv4[1] * xv[t];
            acc[2][t] += wv4[2] * xv[t];
        }
    }

    // pack pairs -> u32 LDS stores
    #pragma unroll
    for (int p = 0; p < 3; ++p) {
        #pragma unroll
        for (int i = 0; i < 2; ++i) {
            unsigned pk = (unsigned)f2bf(acc[p][2 * i]) | ((unsigned)f2bf(acc[p][2 * i + 1]) << 16);
            *(unsigned*)&Ot[lane + 64 * p][t0 + 2 * i] = pk;
        }
    }
    __syncthreads();

    // g + theta (rows 0..127) -> PB channel-major, 16B chunks
    {
        int row = tid >> 2, ch = tid & 3;    // 512 threads = 128 rows x 4 chunks
        uint4 v = *(const uint4*)&Ot[row][ch * 8];
        *(uint4*)(PB + (size_t)b * CC * NSP + (size_t)row * NSP + n0 + ch * 8) = v;
    }
    // phi (rows 128..191) -> token-major
    if (tid < 256) {
        int t = tid >> 3, c8 = (tid & 7) * 8;
        union { u16 tmp[8]; uint4 v4; } u;
        #pragma unroll
        for (int j = 0; j < 8; ++j) u.tmp[j] = Ot[128 + c8 + j][t];
        *(uint4*)(ph_tm + ((size_t)b * NSP + n0 + t) * 64 + c8) = u.v4;
    }
}

// -------------------- Kernel 2: MFMA attention, LDS-staged K/V ------------------
// grid (NSP/64, NB), block 512 = 8 waves: q-strip s=w&3 (16 rows), KV-half h=w>>2.
// Double-buffered K/V staging; shift-softmax p = exp2(QK - 32) via MFMA C-init.
// P strip: 160B rows + XOR chunk swizzle (chunk ^= (row>>1)&7) -> conflict-free.
__global__ __launch_bounds__(512, 2) void attn_kernel(
    const u16* __restrict__ PB, const u16* __restrict__ ph_tm,
    float* __restrict__ y)
{
    const int b    = blockIdx.y;
    const int q0   = blockIdx.x << 6;
    const int tid  = threadIdx.x;
    const int lane = tid & 63;
    const int w    = tid >> 6;       // 0..7
    const int s    = w & 3;          // q strip
    const int h    = w >> 2;         // kv half
    const int l15  = lane & 15;
    const int g16  = lane >> 4;

    __shared__ __align__(16) char KV[2][2][2][8192];
    __shared__ __align__(16) u16 Plds[8][16][80];
    __shared__ float Om[4][16][68];
    __shared__ float Lm[4][16];

    const u16* gp  = PB + (size_t)b * CC * NSP;           // g  cm [64][NSP]
    const u16* thc = gp + (size_t)CIC * NSP;              // theta cm (log2e-scaled)
    const u16* php = ph_tm + (size_t)b * NSP * 64;        // phi tm [NSP][64]

    const int srow = tid >> 3;
    const int scol = tid & 7;
    const int ldst = srow * 128 + (((scol ^ (srow & 7)) & 7) << 4);

    float4 rK0, rK1, rV0, rV1;
    auto load_t = [&](int t) {
        const int m0 = t << 6;
        rK0 = *(const float4*)(php + ((size_t)(       m0 + srow) << 6) + (scol << 3));
        rK1 = *(const float4*)(php + ((size_t)(2048 + m0 + srow) << 6) + (scol << 3));
        rV0 = *(const float4*)(gp + (size_t)srow * NSP +        m0 + (scol << 3));
        rV1 = *(const float4*)(gp + (size_t)srow * NSP + 2048 + m0 + (scol << 3));
    };
    auto write_t = [&](int buf) {
        *(float4*)(&KV[buf][0][0][0] + ldst) = rK0;
        *(float4*)(&KV[buf][0][1][0] + ldst) = rK1;
        *(float4*)(&KV[buf][1][0][0] + ldst) = rV0;
        *(float4*)(&KV[buf][1][1][0] + ldst) = rV1;
    };

    // Q fragments (once)
    s8bf qa0, qa1;
    const int qtok = q0 + s * 16 + l15;
    #pragma unroll
    for (int j = 0; j < 8; ++j) {
        qa0[j] = (short)thc[(size_t)(g16 * 8 + j) * NSP + qtok];
        qa1[j] = (short)thc[(size_t)(32 + g16 * 8 + j) * NSP + qtok];
    }

    const s8bf ones = {0x3F80, 0x3F80, 0x3F80, 0x3F80, 0x3F80, 0x3F80, 0x3F80, 0x3F80};
    const f32x4 cinit = {-32.f, -32.f, -32.f, -32.f};

    f32x4 Ov[4];
    f32x4 lr = (f32x4){0.f, 0.f, 0.f, 0.f};
    #pragma unroll
    for (int c = 0; c < 4; ++c) Ov[c] = (f32x4){0.f, 0.f, 0.f, 0.f};

    load_t(0); write_t(0); load_t(1);
    __syncthreads();

    // P swizzle constants for this lane
    const int pin    = l15 & 7;                 // within-chunk element
    const int pchb   = l15 >> 3;                // chunk base bit
    const int rmask  = (g16 ^ ((l15 >> 1) & 7)) << 3;        // pa0 read offset
    const int rmask1 = ((4 + g16) ^ ((l15 >> 1) & 7)) << 3;  // pa1 read offset

    for (int t = 0; t < 32; ++t) {
        const int buf = t & 1;
        const char* Kb = &KV[buf][0][h][0];
        const char* Vb = &KV[buf][1][h][0];

        // ---- QK^T from swizzled LDS K tile ----
        f32x4 sv[4];
        __builtin_amdgcn_s_setprio(1);
        #pragma unroll
        for (int c = 0; c < 4; ++c) {
            const int tok = c * 16 + l15;
            const int sx  = (tok & 7) << 4;
            s8bf k0 = *(const s8bf*)(Kb + tok * 128 + ((g16 * 16)      ^ sx));
            s8bf k1 = *(const s8bf*)(Kb + tok * 128 + ((g16 * 16 + 64) ^ sx));
            sv[c] = MFMA(qa0, k0, cinit);
            sv[c] = MFMA(qa1, k1, sv[c]);
        }
        __builtin_amdgcn_s_setprio(0);

        // ---- p = exp2(s) -> swizzled bf16 P strip (known-good f2bf path) ----
        u16 (&Pl)[16][80] = Plds[w];
        #pragma unroll
        for (int c = 0; c < 4; ++c) {
            #pragma unroll
            for (int r = 0; r < 4; ++r) {
                const int row = g16 * 4 + r;
                const int swc = ((c * 2 + pchb) ^ ((row >> 1) & 7)) << 3;
                Pl[row][swc | pin] = f2bf(__builtin_amdgcn_exp2f(sv[c][r]));
            }
        }

        // ---- P fragments; l via ones-MFMA; PV from swizzled LDS V tile ----
        s8bf pa0 = *(const s8bf*)&Pl[l15][rmask];
        s8bf pa1 = *(const s8bf*)&Pl[l15][rmask1];
        __builtin_amdgcn_s_setprio(1);
        lr = MFMA(pa0, ones, lr);
        lr = MFMA(pa1, ones, lr);
        #pragma unroll
        for (int c = 0; c < 4; ++c) {
            const int ci = c * 16 + l15;
            const int sx = (ci & 7) << 4;
            s8bf v0 = *(const s8bf*)(Vb + ci * 128 + ((g16 * 16)      ^ sx));
            s8bf v1 = *(const s8bf*)(Vb + ci * 128 + ((g16 * 16 + 64) ^ sx));
            Ov[c] = MFMA(pa0, v0, Ov[c]);
            Ov[c] = MFMA(pa1, v1, Ov[c]);
        }
        __builtin_amdgcn_s_setprio(0);

        if (t < 31) {
            write_t(buf ^ 1);
            if (t < 30) load_t(t + 2);
        }
        __syncthreads();
    }

    // ---- merge the 2 KV halves (plain adds; no max state) ----
    if (h == 1) {
        #pragma unroll
        for (int c = 0; c < 4; ++c) {
            #pragma unroll
            for (int r = 0; r < 4; ++r)
                Om[s][g16 * 4 + r][c * 16 + l15] = Ov[c][r];
        }
        if (l15 == 0) {
            #pragma unroll
            for (int r = 0; r < 4; ++r) Lm[s][g16 * 4 + r] = lr[r];
        }
    }
    __syncthreads();
    if (h == 0) {
        float inv[4];
        #pragma unroll
        for (int r = 0; r < 4; ++r) inv[r] = 1.0f / (lr[r] + Lm[s][g16 * 4 + r]);
        #pragma unroll
        for (int c = 0; c < 4; ++c) {
            #pragma unroll
            for (int r = 0; r < 4; ++r) {
                int row = g16 * 4 + r, col = c * 16 + l15;
                Om[s][row][col] = (Ov[c][r] + Om[s][row][col]) * inv[r];
            }
        }
    }
    __syncthreads();

    // ---- coalesced y write: 64 ci x 64 q ----
    #pragma unroll
    for (int k = 0; k < 2; ++k) {
        int idx = tid + (k << 9);
        int ci = idx >> 4, q4 = (idx & 15) << 2;
        int ss = q4 >> 4, r0 = q4 & 15;
        float4 v;
        v.x = Om[ss][r0][ci]; v.y = Om[ss][r0 + 1][ci];
        v.z = Om[ss][r0 + 2][ci]; v.w = Om[ss][r0 + 3][ci];
        *(float4*)&y[((size_t)b * CIC + ci) * NSP + q0 + q4] = v;
    }
}

// -------------------- Kernel 3: W 1x1 conv -> w_y into d_out --------------------
// grid (NSP/32, NB), block 256 = 4 waves; wave -> 8 tokens, lane -> 2 out-chans.
__global__ __launch_bounds__(256) void wconv_kernel(
    const float* __restrict__ y, const float* __restrict__ wT2p,
    const float* __restrict__ w_b, float* __restrict__ out)
{
    __shared__ float Ys[CIC][36];   // 9.2 KB
    __shared__ float Of[CC][36];    // 18.4 KB

    const int b    = blockIdx.y;
    const int n0   = blockIdx.x * 32;
    const int tid  = threadIdx.x;
    const int lane = tid & 63;
    const int wv   = tid >> 6;
    const int t0   = wv * 8;

    const float* yb = y + (size_t)b * CIC * NSP + n0;
    #pragma unroll
    for (int k = 0; k < 2; ++k) {
        int idx = tid + (k << 8);          // 0..511
        int c = idx >> 3, t4 = (idx & 7) << 2;
        *(f32x4*)&Ys[c][t4] = *(const f32x4*)(yb + (size_t)c * NSP + t4);
    }
    __syncthreads();

    float acc[2][8];
    #pragma unroll
    for (int t = 0; t < 8; ++t) { acc[0][t] = 0.f; acc[1][t] = 0.f; }

    const float* wp = wT2p + (lane << 1);
    #pragma unroll 8
    for (int ci = 0; ci < CIC; ++ci) {
        f32x2 wv2 = *(const f32x2*)(wp + (ci << 7));
        f32x4 y0 = *(const f32x4*)&Ys[ci][t0];
        f32x4 y1 = *(const f32x4*)&Ys[ci][t0 + 4];
        #pragma unroll
        for (int t = 0; t < 4; ++t) {
            acc[0][t]     += wv2[0] * y0[t];
            acc[0][4 + t] += wv2[0] * y1[t];
            acc[1][t]     += wv2[1] * y0[t];
            acc[1][4 + t] += wv2[1] * y1[t];
        }
    }

    float b0 = w_b[lane], b1 = w_b[64 + lane];
    #pragma unroll
    for (int t = 0; t < 4; ++t) {
        Of[lane][t0 + t]          = acc[0][t] + b0;
        Of[lane][t0 + 4 + t]      = acc[0][4 + t] + b0;
        Of[64 + lane][t0 + t]     = acc[1][t] + b1;
        Of[64 + lane][t0 + 4 + t] = acc[1][4 + t] + b1;
    }
    __syncthreads();

    float* ob = out + (size_t)b * CC * NSP + n0;
    #pragma unroll
    for (int k = 0; k < 4; ++k) {
        int idx = tid + (k << 8);          // 0..1023
        int row = idx >> 3, ch = idx & 7;
        *(float4*)(ob + (size_t)row * NSP + ch * 4) = *(const float4*)&Of[row][ch * 4];
    }
}

// -------------------- Kernel 4: per-channel partial stats -----------------------
__global__ __launch_bounds__(256) void stats_kernel(
    const float* __restrict__ wy, float* __restrict__ parts)
{
    const int c   = blockIdx.x >> 2;
    const int qd  = blockIdx.x & 3;
    const int tid = threadIdx.x;
    float s = 0.f, ss = 0.f;
    #pragma unroll 4
    for (int k = 0; k < 16; ++k) {
        int i = qd * 4096 + k * 256 + tid;
        int b = i >> 12, n = i & (NSP - 1);
        float v = wy[((size_t)b * CC + c) * NSP + n];
        s += v; ss += v * v;
    }
    #pragma unroll
    for (int off = 32; off > 0; off >>= 1) {
        s  += __shfl_down(s, off, 64);
        ss += __shfl_down(ss, off, 64);
    }
    __shared__ float sred[4], ssred[4];
    const int wid = tid >> 6, lane = tid & 63;
    if (lane == 0) { sred[wid] = s; ssred[wid] = ss; }
    __syncthreads();
    if (tid == 0) {
        parts[(c * 4 + qd) * 2]     = sred[0] + sred[1] + sred[2] + sred[3];
        parts[(c * 4 + qd) * 2 + 1] = ssred[0] + ssred[1] + ssred[2] + ssred[3];
    }
}

// -------------------- Kernel 5: BN finalize + residual (in-place) ---------------
__global__ __launch_bounds__(256) void bn_kernel(
    const float* __restrict__ x, const float* __restrict__ parts,
    const float* __restrict__ gamma, const float* __restrict__ beta,
    float* __restrict__ out)
{
    const int i = blockIdx.x * 256 + threadIdx.x;
    const int c = (i >> 10) & (CC - 1);
    float s  = parts[c * 8]     + parts[c * 8 + 2] + parts[c * 8 + 4] + parts[c * 8 + 6];
    float ss = parts[c * 8 + 1] + parts[c * 8 + 3] + parts[c * 8 + 5] + parts[c * 8 + 7];
    float mean = s * (1.0f / 16384.0f);
    float var  = ss * (1.0f / 16384.0f) - mean * mean;
    float istd = rsqrtf(var + 1e-5f);
    float ga = gamma[c] * istd;
    float be = beta[c] - mean * ga;
    float4 wy = ((const float4*)out)[i];
    float4 xv = ((const float4*)x)[i];
    float4 o;
    o.x = wy.x * ga + be + xv.x;
    o.y = wy.y * ga + be + xv.y;
    o.z = wy.z * ga + be + xv.z;
    o.w = wy.w * ga + be + xv.w;
    ((float4*)out)[i] = o;
}

extern "C" void kernel_launch(void* const* d_in, const int* in_sizes, int n_in,
                              void* d_out, int out_size, void* d_ws, size_t ws_size,
                              hipStream_t stream)
{
    const float* x    = (const float*)d_in[0];
    const float* g_w  = (const float*)d_in[1];
    const float* g_b  = (const float*)d_in[2];
    const float* t_w  = (const float*)d_in[3];
    const float* t_b  = (const float*)d_in[4];
    const float* p_w  = (const float*)d_in[5];
    const float* p_b  = (const float*)d_in[6];
    const float* w_w  = (const float*)d_in[7];
    const float* w_b  = (const float*)d_in[8];
    const float* bn_g = (const float*)d_in[9];
    const float* bn_b = (const float*)d_in[10];
    float* out = (float*)d_out;
    char* ws8  = (char*)d_ws;

    u16*   PB    = (u16*)(ws8 + WSB_PB);
    u16*   PH    = (u16*)(ws8 + WSB_PH);
    float* y     = (float*)(ws8 + WSB_Y);
    float* wT4   = (float*)(ws8 + WSB_WT4);
    float* wT2p  = (float*)(ws8 + WSB_WT2P);
    float* parts = (float*)(ws8 + WSB_PARTS);

    prep_kernel <<<dim3(CC), 256, 0, stream>>>(g_w, t_w, p_w, w_w, wT4, wT2p);
    proj_kernel <<<dim3(NSP / 32, NB), 512, 0, stream>>>(x, wT4, g_b, t_b, p_b, PB, PH);
    attn_kernel <<<dim3(NSP / 64, NB), 512, 0, stream>>>(PB, PH, y);
    wconv_kernel<<<dim3(NSP / 32, NB), 256, 0, stream>>>(y, wT2p, w_b, out);
    stats_kernel<<<dim3(CC * 4), 256, 0, stream>>>(out, parts);
    bn_kernel   <<<dim3(2048), 256, 0, stream>>>(x, parts, bn_g, bn_b, out);
}